// Round 6
// baseline (644.153 us; speedup 1.0000x reference)
//
#include <hip/hip_runtime.h>
#include <hip/hip_bf16.h>

#define NN 50000
#define EE 800000
#define FIN 500
#define H1D 300
#define H2D 100
#define CC 16

// ---------- dtype-flexible load helpers ----------
__device__ __forceinline__ float ldf(const void* p, size_t i, int isbf16) {
    return isbf16 ? __bfloat162float(((const __hip_bfloat16*)p)[i])
                  : ((const float*)p)[i];
}
__device__ __forceinline__ int ld_src(const int* ei, int e, int is64) {
    return is64 ? ei[2 * (size_t)e] : ei[e];
}
__device__ __forceinline__ int ld_dst(const int* ei, int e, int is64) {
    return is64 ? ei[2 * ((size_t)EE + e)] : ei[(size_t)EE + e];
}

// split fp32 -> hi/lo bf16 (hi+lo captures ~17 mantissa bits)
__device__ __forceinline__ void split2(float f, unsigned short& h, unsigned short& l) {
    __bf16 hb = (__bf16)f;
    float fh = (float)hb;
    __bf16 lb = (__bf16)(f - fh);
    h = __builtin_bit_cast(unsigned short, hb);
    l = __builtin_bit_cast(unsigned short, lb);
}

// unpack 2 packed bf16 to float2
__device__ __forceinline__ float2 bf2f2(unsigned int v) {
    float lo = __builtin_bit_cast(float, v << 16);
    float hi = __builtin_bit_cast(float, v & 0xffff0000u);
    return make_float2(lo, hi);
}

typedef __bf16 bf16x8 __attribute__((ext_vector_type(8)));
typedef float f32x4 __attribute__((ext_vector_type(4)));
typedef unsigned short u16x8 __attribute__((ext_vector_type(8)));

__device__ __forceinline__ void split8(const float4& v0, const float4& v1,
                                       bf16x8& h8, bf16x8& l8) {
    float f[8] = {v0.x, v0.y, v0.z, v0.w, v1.x, v1.y, v1.z, v1.w};
    u16x8 hv, lv;
#pragma unroll
    for (int i = 0; i < 8; i++) {
        unsigned short h, l;
        split2(f[i], h, l);
        hv[i] = h; lv[i] = l;
    }
    h8 = __builtin_bit_cast(bf16x8, hv);
    l8 = __builtin_bit_cast(bf16x8, lv);
}

// ---------- dtype sniffing ----------
__global__ void k_sniff(const unsigned short* __restrict__ xw,
                        const unsigned int* __restrict__ ew,
                        int* __restrict__ flags) {
    __shared__ int c_sane, c_zero;
    if (threadIdx.x == 0) { c_sane = 0; c_zero = 0; }
    __syncthreads();
    int t = threadIdx.x;
    int sane = 0, zer = 0;
    for (int j = 0; j < 4; j++) {
        unsigned short w = xw[t * 4 + j];
        int ex = (w >> 7) & 0xFF;
        if (w == 0 || (ex >= 100 && ex <= 150)) sane++;
        if (ew[2 * (t * 4 + j) + 1] == 0u) zer++;
    }
    atomicAdd(&c_sane, sane);
    atomicAdd(&c_zero, zer);
    __syncthreads();
    if (threadIdx.x == 0) {
        flags[0] = (c_sane > 820) ? 1 : 0;
        flags[1] = (c_zero > 512) ? 1 : 0;
    }
}

// ---------- degree / CSR build ----------
__global__ void k_zero_cnt(int* __restrict__ cnt) {
    int i = blockIdx.x * blockDim.x + threadIdx.x;
    if (i < NN) cnt[i] = 0;
}

__global__ void k_hist(const int* __restrict__ ei, int* __restrict__ cnt,
                       const int* __restrict__ flags) {
    int e = blockIdx.x * blockDim.x + threadIdx.x;
    int is64 = flags[1];
    if (e < EE) {
        int d = ld_dst(ei, e, is64);
        if ((unsigned)d < NN) atomicAdd(&cnt[d], 1);
    }
}

// scan + dinv fused (dinv from original counts, cnt reset for scatter fill)
__global__ __launch_bounds__(1024) void k_scan(int* __restrict__ cnt, int* __restrict__ row_ptr,
                                               float* __restrict__ dinv) {
    const int T = 1024;
    const int chunk = (NN + T - 1) / T;  // 49
    int t = threadIdx.x;
    int lo = t * chunk;
    int hi = lo + chunk; if (hi > NN) hi = NN; if (lo > NN) lo = NN;
    int s = 0;
    for (int i = lo; i < hi; i++) {
        int c = cnt[i];
        s += c;
        dinv[i] = rsqrtf((float)c + 1.0f);  // +1 self loop
    }
    __shared__ int sums[T];
    sums[t] = s;
    __syncthreads();
    for (int off = 1; off < T; off <<= 1) {
        int v = (t >= off) ? sums[t - off] : 0;
        __syncthreads();
        sums[t] += v;
        __syncthreads();
    }
    int run = sums[t] - s;
    for (int i = lo; i < hi; i++) {
        int c = cnt[i];
        row_ptr[i] = run;
        run += c;
        cnt[i] = 0;
    }
    if (t == T - 1) row_ptr[NN] = run;
}

__global__ void k_scatter(const int* __restrict__ ei, const int* __restrict__ row_ptr,
                          int* __restrict__ fill, int* __restrict__ csr_src,
                          const int* __restrict__ flags) {
    int e = blockIdx.x * blockDim.x + threadIdx.x;
    int is64 = flags[1];
    if (e < EE) {
        int s = ld_src(ei, e, is64);
        int d = ld_dst(ei, e, is64);
        if ((unsigned)d < NN) {
            int pos = row_ptr[d] + atomicAdd(&fill[d], 1);
            csr_src[pos] = s;
        }
    }
}

// ---------- bf16-input fallback tiled GEMM (runs only when flags[0]==1) ----------
template <bool A_DYN, bool RELU, bool SCALE, bool OUTBF>
__global__ __launch_bounds__(256) void k_gemm(const void* __restrict__ A,
                                              const void* __restrict__ B,
                                              const void* __restrict__ bias,
                                              const float* __restrict__ dinv,
                                              void* __restrict__ C,
                                              int M, int K, int Nn,
                                              const int* __restrict__ flags) {
    if (!flags[0]) return;
    __shared__ float As[16][68];
    __shared__ float Bs[16][68];
    const int bf = flags[0];
    const int tid = threadIdx.x;
    const int m0 = blockIdx.x * 64, n0 = blockIdx.y * 64;
    const int tx = tid & 15;
    const int ty = tid >> 4;
    float acc[4][4] = {};

    for (int kc = 0; kc < K; kc += 16) {
#pragma unroll
        for (int j = 0; j < 4; j++) {
            int idx = tid + j * 256;
            int kk = idx & 15, mm = idx >> 4;
            int gm = m0 + mm, gk = kc + kk;
            float v = 0.0f;
            if (gm < M && gk < K) {
                size_t o = (size_t)gm * K + gk;
                v = A_DYN ? ldf(A, o, bf) : ((const float*)A)[o];
            }
            As[kk][mm] = v;
        }
#pragma unroll
        for (int j = 0; j < 4; j++) {
            int idx = tid + j * 256;
            int nn = idx & 63, kk = idx >> 6;
            int gk = kc + kk, gn = n0 + nn;
            Bs[kk][nn] = (gk < K && gn < Nn) ? ldf(B, (size_t)gk * Nn + gn, bf) : 0.0f;
        }
        __syncthreads();
#pragma unroll
        for (int kk = 0; kk < 16; kk++) {
            float4 a4 = *(const float4*)&As[kk][ty * 4];
            float4 b4 = *(const float4*)&Bs[kk][tx * 4];
            float av[4] = {a4.x, a4.y, a4.z, a4.w};
            float bv[4] = {b4.x, b4.y, b4.z, b4.w};
#pragma unroll
            for (int i = 0; i < 4; i++)
#pragma unroll
                for (int j = 0; j < 4; j++) acc[i][j] += av[i] * bv[j];
        }
        __syncthreads();
    }

#pragma unroll
    for (int i = 0; i < 4; i++) {
        int m = m0 + ty * 4 + i;
        if (m >= M) continue;
        float sc = SCALE ? dinv[m] : 1.0f;
#pragma unroll
        for (int j = 0; j < 4; j++) {
            int n = n0 + tx * 4 + j;
            if (n >= Nn) continue;
            float v = acc[i][j];
            if (bias) v += ldf(bias, n, bf);
            if (SCALE) v *= sc;
            if (RELU) v = fmaxf(v, 0.0f);
            if (OUTBF) ((__hip_bfloat16*)C)[(size_t)m * Nn + n] = __float2bfloat16(v);
            else       ((float*)C)[(size_t)m * Nn + n] = v;
        }
    }
}

// ---------- B prep: W[K,Nn] fp32 -> Bt[NnPad][2*Kp] bf16 ([hi|lo], transposed, zero-pad) ----------
__global__ __launch_bounds__(256) void k_prep_b(const float* __restrict__ W,
                                                unsigned short* __restrict__ Bt,
                                                int K, int Nn, int Kp, int NnPad,
                                                const int* __restrict__ flags) {
    if (flags[0]) return;
    int idx = blockIdx.x * 256 + threadIdx.x;
    if (idx >= NnPad * Kp) return;
    int n = idx / Kp, k = idx - n * Kp;
    float v = (n < Nn && k < K) ? W[(size_t)k * Nn + n] : 0.0f;
    unsigned short h, l;
    split2(v, h, l);
    Bt[(size_t)n * (2 * Kp) + k] = h;
    Bt[(size_t)n * (2 * Kp) + Kp + k] = l;
}

// ---------- no-LDS split-bf16 MFMA GEMM ----------
// Operand panels are L1/L2-resident -> skip LDS staging entirely (no barriers, no
// vmcnt(0) drains; waves independent, TLP hides latency). Fragments loaded direct:
// B (and pre-split A) as 16B uint4; fp32 A as 2x float4 + in-reg split.
// Tile 128x128, 4 waves 2x2, per-wave 64x64 = 4x4 frags of 16x16x32. XCD swizzle kept.
template <bool ASPLIT, bool RELU, bool SCALE, bool HAS_BIAS, int OUTMODE, int KT, int KPT, int AKT>
__global__ __launch_bounds__(256) void k_gemm_reg(
        const void* __restrict__ Aa, const void* __restrict__ Ab,   // ASPLIT: Aa=fp32; else hi/lo planes
        const unsigned short* __restrict__ Bt,
        const float* __restrict__ bias, const float* __restrict__ dinv,
        void* __restrict__ Ca, void* __restrict__ Cb,               // OUTMODE2: hi/lo planes; else out
        int M, int NnOut, int NnPad,
        const int* __restrict__ flags) {
    if (flags[0]) return;
    const int tid = threadIdx.x;
    // bijective XCD-aware swizzle: same-XCD-consecutive work ids share the A m-panel
    const int nbx = gridDim.x;
    const int Wt = nbx * gridDim.y;
    const int li = blockIdx.x + nbx * blockIdx.y;
    const int q8 = Wt >> 3, r8 = Wt & 7;
    const int xk = li & 7, xj = li >> 3;
    const int wid = (xk < r8 ? xk * (q8 + 1) : r8 * (q8 + 1) + (xk - r8) * q8) + xj;
    const int n0 = (wid % nbx) * 128;
    const int m0 = (wid / nbx) * 128;
    const int w = tid >> 6, l = tid & 63;
    const int wm = (w >> 1) * 64, wn = (w & 1) * 64;
    const int lr = l & 15, ls = l >> 4;
    f32x4 acc[4][4] = {};

    const int nsteps = (KT + 31) / 32;
    for (int kt = 0; kt < nsteps; kt++) {
        const int kc = kt * 32;
        bf16x8 ah[4], al[4], bh[4], bl[4];
        // B fragments: 16B chunks straight from pre-split planes (L2-hit)
#pragma unroll
        for (int fn = 0; fn < 4; fn++) {
            int gn = n0 + wn + fn * 16 + lr;
            const unsigned short* pb = Bt + (size_t)gn * (2 * KPT) + kc + ls * 8;
            bh[fn] = __builtin_bit_cast(bf16x8, *(const uint4*)pb);
            bl[fn] = __builtin_bit_cast(bf16x8, *(const uint4*)(pb + KPT));
        }
        // A fragments
#pragma unroll
        for (int fm = 0; fm < 4; fm++) {
            int gm = m0 + wm + fm * 16 + lr;
            if (ASPLIT) {
                const float* ap = (const float*)Aa + (size_t)gm * AKT + kc + ls * 8;
                int gk = kc + ls * 8;
                float4 v0 = make_float4(0.f, 0.f, 0.f, 0.f), v1 = v0;
                if (gm < M && gk < KT) v0 = *(const float4*)ap;
                if (gm < M && gk + 4 < KT) v1 = *(const float4*)(ap + 4);
                split8(v0, v1, ah[fm], al[fm]);
            } else {
                const unsigned short* ph = (const unsigned short*)Aa + (size_t)gm * AKT + kc + ls * 8;
                const unsigned short* pl = (const unsigned short*)Ab + (size_t)gm * AKT + kc + ls * 8;
                uint4 vh = make_uint4(0u, 0u, 0u, 0u), vl = vh;
                if (gm < M) { vh = *(const uint4*)ph; vl = *(const uint4*)pl; }
                ah[fm] = __builtin_bit_cast(bf16x8, vh);
                al[fm] = __builtin_bit_cast(bf16x8, vl);
            }
        }
#pragma unroll
        for (int fm = 0; fm < 4; fm++)
#pragma unroll
            for (int fn = 0; fn < 4; fn++) {
                acc[fm][fn] = __builtin_amdgcn_mfma_f32_16x16x32_bf16(ah[fm], bh[fn], acc[fm][fn], 0, 0, 0);
                acc[fm][fn] = __builtin_amdgcn_mfma_f32_16x16x32_bf16(ah[fm], bl[fn], acc[fm][fn], 0, 0, 0);
                acc[fm][fn] = __builtin_amdgcn_mfma_f32_16x16x32_bf16(al[fm], bh[fn], acc[fm][fn], 0, 0, 0);
            }
    }

    // epilogue: C/D layout col=lane&15, row=(lane>>4)*4+reg [m89-verified]
#pragma unroll
    for (int fm = 0; fm < 4; fm++) {
#pragma unroll
        for (int j = 0; j < 4; j++) {
            int m = m0 + wm + fm * 16 + ls * 4 + j;
            if (m >= M) continue;
            float sc = SCALE ? dinv[m] : 1.0f;
#pragma unroll
            for (int fn = 0; fn < 4; fn++) {
                int n = n0 + wn + fn * 16 + lr;
                if (OUTMODE == 2) {
                    // pre-split hi/lo planes (pad cols zeroed)
                    if (n >= NnPad) continue;
                    float v = 0.0f;
                    if (n < NnOut) {
                        v = acc[fm][fn][j];
                        if (HAS_BIAS) v += bias[n];
                        if (SCALE) v *= sc;
                        if (RELU) v = fmaxf(v, 0.0f);
                    }
                    unsigned short h, lo2;
                    split2(v, h, lo2);
                    ((unsigned short*)Ca)[(size_t)m * NnPad + n] = h;
                    ((unsigned short*)Cb)[(size_t)m * NnPad + n] = lo2;
                } else {
                    if (n >= NnOut) continue;
                    float v = acc[fm][fn][j];
                    if (HAS_BIAS) v += bias[n];
                    if (SCALE) v *= sc;
                    if (RELU) v = fmaxf(v, 0.0f);
                    if (OUTMODE == 1)
                        ((__hip_bfloat16*)Ca)[(size_t)m * NnOut + n] = __float2bfloat16(v);
                    else
                        ((float*)Ca)[(size_t)m * NnOut + n] = v;
                }
            }
        }
    }
}

// ---------- agg1 + gemm3 fused: h2p = ((AGG(h1p)+b1).relu @ W2) * dinv ----------
// wave per node; gather phase 50 lanes (2 bf16 feats/lane); dot phase all 64 lanes
// (4 k-groups x 16 outputs) via wave-local LDS row + 2 shfl reduce. H2 never hits HBM.
__global__ __launch_bounds__(256) void k_agg1_fused(const unsigned short* __restrict__ h1p_bf,
                                                    const int* __restrict__ row_ptr,
                                                    const int* __restrict__ csr_src,
                                                    const float* __restrict__ dinv,
                                                    const void* __restrict__ b1,
                                                    const void* __restrict__ W2,
                                                    float* __restrict__ h2p,
                                                    const int* __restrict__ flags) {
    __shared__ float W2s[16][105];  // [n][k], padded stride -> conflict-free lane reads
    __shared__ float b1s[H2D];
    __shared__ float Hrow[4][H2D];
    const int bf = flags[0];
    const int tid = threadIdx.x;
    for (int i = tid; i < H2D * CC; i += 256) {
        int k = i >> 4, n = i & 15;
        W2s[n][k] = ldf(W2, i, bf);
    }
    for (int i = tid; i < H2D; i += 256) b1s[i] = ldf(b1, i, bf);
    __syncthreads();

    const int w = tid >> 6, lane = tid & 63;
    const int q = lane >> 4, n16 = lane & 15;
    const unsigned int* rows = (const unsigned int*)h1p_bf;  // 50 uints/node
    for (int node = blockIdx.x * 4 + w; node < NN; node += gridDim.x * 4) {
        float di = dinv[node];
        if (lane < 50) {
            float2 s = bf2f2(rows[(size_t)node * 50 + lane]);  // self loop
            float a0x = s.x, a0y = s.y;
            float a1x = 0.f, a1y = 0.f, a2x = 0.f, a2y = 0.f, a3x = 0.f, a3y = 0.f;
            int lo = row_ptr[node], hi = row_ptr[node + 1];
            int e = lo;
            for (; e + 3 < hi; e += 4) {
                int s0 = csr_src[e], s1 = csr_src[e + 1], s2 = csr_src[e + 2], s3 = csr_src[e + 3];
                float2 v0 = bf2f2(rows[(size_t)s0 * 50 + lane]);
                float2 v1 = bf2f2(rows[(size_t)s1 * 50 + lane]);
                float2 v2 = bf2f2(rows[(size_t)s2 * 50 + lane]);
                float2 v3 = bf2f2(rows[(size_t)s3 * 50 + lane]);
                a0x += v0.x; a0y += v0.y;
                a1x += v1.x; a1y += v1.y;
                a2x += v2.x; a2y += v2.y;
                a3x += v3.x; a3y += v3.y;
            }
            for (; e < hi; e++) {
                float2 v = bf2f2(rows[(size_t)csr_src[e] * 50 + lane]);
                a0x += v.x; a0y += v.y;
            }
            float sx = (a0x + a1x) + (a2x + a3x);
            float sy = (a0y + a1y) + (a2y + a3y);
            int f = lane * 2;
            Hrow[w][f]     = fmaxf(sx * di + b1s[f], 0.0f);
            Hrow[w][f + 1] = fmaxf(sy * di + b1s[f + 1], 0.0f);
        }
        __builtin_amdgcn_sched_barrier(0);  // wave-local: DS ops in-order within a wave
        float acc2 = 0.0f;
#pragma unroll
        for (int j = 0; j < 25; j++) {
            int k = q * 25 + j;
            acc2 += Hrow[w][k] * W2s[n16][k];
        }
        acc2 += __shfl_xor(acc2, 16);
        acc2 += __shfl_xor(acc2, 32);
        if (lane < 16) h2p[(size_t)node * CC + n16] = acc2 * di;
        __builtin_amdgcn_sched_barrier(0);
    }
}

// ---------- aggregation 2 + bias + log_softmax (4-deep edge unroll) ----------
__global__ __launch_bounds__(256) void k_agg2(const float* __restrict__ h2p,
                                              const int* __restrict__ row_ptr,
                                              const int* __restrict__ csr_src,
                                              const float* __restrict__ dinv,
                                              const void* __restrict__ b2,
                                              void* __restrict__ out,
                                              const int* __restrict__ flags) {
    int tid = threadIdx.x;
    int n = tid & 15;
    int g = tid >> 4;
    int node = blockIdx.x * 16 + g;
    if (node >= NN) return;
    const int bf = flags[0];
    float a0 = h2p[(size_t)node * CC + n];
    float a1 = 0.f, a2 = 0.f, a3 = 0.f;
    int lo = row_ptr[node], hi = row_ptr[node + 1];
    int e = lo;
    for (; e + 3 < hi; e += 4) {
        int s0 = csr_src[e], s1 = csr_src[e + 1], s2 = csr_src[e + 2], s3 = csr_src[e + 3];
        a0 += h2p[(size_t)s0 * CC + n];
        a1 += h2p[(size_t)s1 * CC + n];
        a2 += h2p[(size_t)s2 * CC + n];
        a3 += h2p[(size_t)s3 * CC + n];
    }
    for (; e < hi; e++) a0 += h2p[(size_t)csr_src[e] * CC + n];
    float acc = (a0 + a1) + (a2 + a3);
    float logit = acc * dinv[node] + ldf(b2, n, bf);
    float m = logit;
#pragma unroll
    for (int off = 1; off < 16; off <<= 1) m = fmaxf(m, __shfl_xor(m, off, 16));
    float ex = __expf(logit - m);
    float ssum = ex;
#pragma unroll
    for (int off = 1; off < 16; off <<= 1) ssum += __shfl_xor(ssum, off, 16);
    float r = logit - m - __logf(ssum);
    size_t oidx = (size_t)node * CC + n;
    if (bf) ((__hip_bfloat16*)out)[oidx] = __float2bfloat16(r);
    else    ((float*)out)[oidx] = r;
}

extern "C" void kernel_launch(void* const* d_in, const int* in_sizes, int n_in,
                              void* d_out, int out_size, void* d_ws, size_t ws_size,
                              hipStream_t stream) {
    const void* x     = d_in[0];
    const void* lin_W = d_in[1];
    const void* lin_b = d_in[2];
    const void* W1    = d_in[3];
    const void* b1    = d_in[4];
    const void* W2    = d_in[5];
    const void* b2    = d_in[6];
    const int*  ei    = (const int*)d_in[7];

    char* ws = (char*)d_ws;
    size_t off = 0;
    auto alloc = [&](size_t bytes) {
        off = (off + 255) & ~(size_t)255;
        void* p = ws + off;
        off += bytes;
        return p;
    };
    int*   flags   = (int*)alloc(2 * 4);
    int*   cnt     = (int*)alloc((size_t)NN * 4);
    int*   row_ptr = (int*)alloc((size_t)(NN + 1) * 4);
    int*   csr_src = (int*)alloc((size_t)EE * 4);
    float* dinv    = (float*)alloc((size_t)NN * 4);
    // H1 as pre-split planes [NN][320] hi + lo (fp32-fallback mode overlays as [NN][300] fp32)
    unsigned short* H1h = (unsigned short*)alloc((size_t)NN * 320 * 2);  // 32 MB
    unsigned short* H1l = (unsigned short*)alloc((size_t)NN * 320 * 2);  // 32 MB
    unsigned short* H1p = (unsigned short*)alloc((size_t)NN * H2D * 2);  // 10 MB (bf16)
    float* h2p     = (float*)alloc((size_t)NN * CC * 4);                 // 3.2 MB
    unsigned short* Bt1 = (unsigned short*)alloc((size_t)384 * 1024 * 2);  // [384][2*512]
    unsigned short* Bt2 = (unsigned short*)alloc((size_t)128 * 640 * 2);   // [128][2*320]

    const int gN = (NN + 255) / 256;
    const int gE = (EE + 255) / 256;

    k_sniff<<<1, 256, 0, stream>>>((const unsigned short*)x, (const unsigned int*)ei, flags);

    // CSR + degrees (dinv fused into scan)
    k_zero_cnt<<<gN, 256, 0, stream>>>(cnt);
    k_hist<<<gE, 256, 0, stream>>>(ei, cnt, flags);
    k_scan<<<1, 1024, 0, stream>>>(cnt, row_ptr, dinv);
    k_scatter<<<gE, 256, 0, stream>>>(ei, row_ptr, cnt, csr_src, flags);

    // weight prep for MFMA path (no-op in bf16 mode)
    k_prep_b<<<(384 * 512 + 255) / 256, 256, 0, stream>>>(
        (const float*)lin_W, Bt1, FIN, H1D, 512, 384, flags);
    k_prep_b<<<(128 * 320 + 255) / 256, 256, 0, stream>>>(
        (const float*)W1, Bt2, H1D, H2D, 320, 128, flags);

    // H1 = relu(x @ lin_W + lin_b) -> pre-split hi/lo planes [NN][320]
    k_gemm_reg<true, true, false, true, 2, FIN, 512, FIN>
        <<<dim3(3, (NN + 127) / 128), 256, 0, stream>>>(
            x, nullptr, Bt1, (const float*)lin_b, nullptr,
            H1h, H1l, NN, H1D, 320, flags);
    {   // bf16-input fallback (early-exits in fp32 mode); H1 fp32 overlay in H1h..
        dim3 grid((NN + 63) / 64, (H1D + 63) / 64);
        k_gemm<true, true, false, false><<<grid, 256, 0, stream>>>(
            x, lin_W, lin_b, nullptr, (float*)H1h, NN, FIN, H1D, flags);
    }

    // H1p = (H1 @ W1) * dinv[row] -> bf16 packed; A = pre-split planes, pure-copy operands
    k_gemm_reg<false, false, true, false, 1, 320, 320, 320>
        <<<dim3(1, (NN + 127) / 128), 256, 0, stream>>>(
            H1h, H1l, Bt2, nullptr, dinv,
            H1p, nullptr, NN, H2D, 0, flags);
    {   // bf16-input fallback
        dim3 grid((NN + 63) / 64, (H2D + 63) / 64);
        k_gemm<false, false, true, true><<<grid, 256, 0, stream>>>(
            (float*)H1h, W1, nullptr, dinv, H1p, NN, H1D, H2D, flags);
    }

    // h2p = relu(dinv*AGG(H1p)+b1) @ W2 * dinv   (gemm3 fused in; H2 never materialized)
    k_agg1_fused<<<2048, 256, 0, stream>>>(H1p, row_ptr, csr_src, dinv, b1, W2, h2p, flags);
    // out = log_softmax(dinv * (gather-sum h2p) + b2)
    k_agg2<<<(NN + 15) / 16, 256, 0, stream>>>(h2p, row_ptr, csr_src, dinv, b2, d_out, flags);
}

// Round 7
// 415.636 us; speedup vs baseline: 1.5498x; 1.5498x over previous
//
#include <hip/hip_runtime.h>
#include <hip/hip_bf16.h>

#define NN 50000
#define EE 800000
#define FIN 500
#define H1D 300
#define H2D 100
#define CC 16

// ---------- dtype-flexible load helpers ----------
__device__ __forceinline__ float ldf(const void* p, size_t i, int isbf16) {
    return isbf16 ? __bfloat162float(((const __hip_bfloat16*)p)[i])
                  : ((const float*)p)[i];
}
__device__ __forceinline__ int ld_src(const int* ei, int e, int is64) {
    return is64 ? ei[2 * (size_t)e] : ei[e];
}
__device__ __forceinline__ int ld_dst(const int* ei, int e, int is64) {
    return is64 ? ei[2 * ((size_t)EE + e)] : ei[(size_t)EE + e];
}

// split fp32 -> hi/lo bf16 (hi+lo captures ~17 mantissa bits)
__device__ __forceinline__ void split2(float f, unsigned short& h, unsigned short& l) {
    __bf16 hb = (__bf16)f;
    float fh = (float)hb;
    __bf16 lb = (__bf16)(f - fh);
    h = __builtin_bit_cast(unsigned short, hb);
    l = __builtin_bit_cast(unsigned short, lb);
}

// unpack 2 packed bf16 to float2
__device__ __forceinline__ float2 bf2f2(unsigned int v) {
    float lo = __builtin_bit_cast(float, v << 16);
    float hi = __builtin_bit_cast(float, v & 0xffff0000u);
    return make_float2(lo, hi);
}

typedef __bf16 bf16x8 __attribute__((ext_vector_type(8)));
typedef float f32x4 __attribute__((ext_vector_type(4)));

// ---------- init: sniff dtypes (block 0) + zero cnt (blocks 1..) ----------
// flags[0]=1 if floats bf16; flags[1]=1 if edge_index int64.
__global__ __launch_bounds__(256) void k_init(const unsigned short* __restrict__ xw,
                                              const unsigned int* __restrict__ ew,
                                              int* __restrict__ flags,
                                              int* __restrict__ cnt,
                                              int* __restrict__ total) {
    if (blockIdx.x == 0) {
        __shared__ int c_sane, c_zero;
        if (threadIdx.x == 0) { c_sane = 0; c_zero = 0; }
        __syncthreads();
        int t = threadIdx.x;
        int sane = 0, zer = 0;
        for (int j = 0; j < 4; j++) {
            unsigned short w = xw[t * 4 + j];
            int ex = (w >> 7) & 0xFF;
            if (w == 0 || (ex >= 100 && ex <= 150)) sane++;
            if (ew[2 * (t * 4 + j) + 1] == 0u) zer++;
        }
        atomicAdd(&c_sane, sane);
        atomicAdd(&c_zero, zer);
        __syncthreads();
        if (threadIdx.x == 0) {
            flags[0] = (c_sane > 820) ? 1 : 0;
            flags[1] = (c_zero > 512) ? 1 : 0;
            total[0] = 0;
        }
    } else {
        int i = (blockIdx.x - 1) * 256 + threadIdx.x;
        if (i < NN) cnt[i] = 0;
    }
}

__global__ void k_hist(const int* __restrict__ ei, int* __restrict__ cnt,
                       const int* __restrict__ flags) {
    int e = blockIdx.x * blockDim.x + threadIdx.x;
    int is64 = flags[1];
    if (e < EE) {
        int d = ld_dst(ei, e, is64);
        if ((unsigned)d < NN) atomicAdd(&cnt[d], 1);
    }
}

// ---------- multi-block scan: per-block scan + atomic base. Row regions are
// non-monotone across blocks (legal: agg uses lo + deg). dinv fused; cnt reset. ----------
__global__ __launch_bounds__(256) void k_scan_mb(int* __restrict__ cnt,
                                                 int* __restrict__ row_ptr,
                                                 float* __restrict__ dinv,
                                                 int* __restrict__ total) {
    int t = threadIdx.x;
    int i = blockIdx.x * 256 + t;
    int c = (i < NN) ? cnt[i] : 0;
    __shared__ int s[256];
    s[t] = c;
    __syncthreads();
    for (int off = 1; off < 256; off <<= 1) {
        int v = (t >= off) ? s[t - off] : 0;
        __syncthreads();
        s[t] += v;
        __syncthreads();
    }
    int incl = s[t];
    __shared__ int base;
    if (t == 255) base = atomicAdd(total, s[255]);
    __syncthreads();
    if (i < NN) {
        row_ptr[i] = base + incl - c;
        dinv[i] = rsqrtf((float)c + 1.0f);  // +1 self loop
        cnt[i] = 0;                          // reuse as scatter fill counter (ends = deg)
    }
}

__global__ void k_scatter(const int* __restrict__ ei, const int* __restrict__ row_ptr,
                          int* __restrict__ fill, int* __restrict__ csr_src,
                          const int* __restrict__ flags) {
    int e = blockIdx.x * blockDim.x + threadIdx.x;
    int is64 = flags[1];
    if (e < EE) {
        int s = ld_src(ei, e, is64);
        int d = ld_dst(ei, e, is64);
        if ((unsigned)d < NN) {
            int pos = row_ptr[d] + atomicAdd(&fill[d], 1);
            csr_src[pos] = s;
        }
    }
}

// ---------- bf16-input fallback tiled GEMM (runs only when flags[0]==1) ----------
template <bool A_DYN, bool RELU, bool SCALE, bool OUTBF>
__global__ __launch_bounds__(256) void k_gemm(const void* __restrict__ A,
                                              const void* __restrict__ B,
                                              const void* __restrict__ bias,
                                              const float* __restrict__ dinv,
                                              void* __restrict__ C,
                                              int M, int K, int Nn,
                                              const int* __restrict__ flags) {
    if (!flags[0]) return;
    __shared__ float As[16][68];
    __shared__ float Bs[16][68];
    const int bf = flags[0];
    const int tid = threadIdx.x;
    const int m0 = blockIdx.x * 64, n0 = blockIdx.y * 64;
    const int tx = tid & 15;
    const int ty = tid >> 4;
    float acc[4][4] = {};

    for (int kc = 0; kc < K; kc += 16) {
#pragma unroll
        for (int j = 0; j < 4; j++) {
            int idx = tid + j * 256;
            int kk = idx & 15, mm = idx >> 4;
            int gm = m0 + mm, gk = kc + kk;
            float v = 0.0f;
            if (gm < M && gk < K) {
                size_t o = (size_t)gm * K + gk;
                v = A_DYN ? ldf(A, o, bf) : ((const float*)A)[o];
            }
            As[kk][mm] = v;
        }
#pragma unroll
        for (int j = 0; j < 4; j++) {
            int idx = tid + j * 256;
            int nn = idx & 63, kk = idx >> 6;
            int gk = kc + kk, gn = n0 + nn;
            Bs[kk][nn] = (gk < K && gn < Nn) ? ldf(B, (size_t)gk * Nn + gn, bf) : 0.0f;
        }
        __syncthreads();
#pragma unroll
        for (int kk = 0; kk < 16; kk++) {
            float4 a4 = *(const float4*)&As[kk][ty * 4];
            float4 b4 = *(const float4*)&Bs[kk][tx * 4];
            float av[4] = {a4.x, a4.y, a4.z, a4.w};
            float bv[4] = {b4.x, b4.y, b4.z, b4.w};
#pragma unroll
            for (int i = 0; i < 4; i++)
#pragma unroll
                for (int j = 0; j < 4; j++) acc[i][j] += av[i] * bv[j];
        }
        __syncthreads();
    }

#pragma unroll
    for (int i = 0; i < 4; i++) {
        int m = m0 + ty * 4 + i;
        if (m >= M) continue;
        float sc = SCALE ? dinv[m] : 1.0f;
#pragma unroll
        for (int j = 0; j < 4; j++) {
            int n = n0 + tx * 4 + j;
            if (n >= Nn) continue;
            float v = acc[i][j];
            if (bias) v += ldf(bias, n, bf);
            if (SCALE) v *= sc;
            if (RELU) v = fmaxf(v, 0.0f);
            if (OUTBF) ((__hip_bfloat16*)C)[(size_t)m * Nn + n] = __float2bfloat16(v);
            else       ((float*)C)[(size_t)m * Nn + n] = v;
        }
    }
}

// ---------- fused weight prep: lin_W -> Bt1 [384][2*512]; W1 -> Bt2 [128][2*320] ----------
__global__ __launch_bounds__(256) void k_prep_both(const float* __restrict__ linW,
                                                   const float* __restrict__ W1,
                                                   unsigned short* __restrict__ Bt1,
                                                   unsigned short* __restrict__ Bt2,
                                                   const int* __restrict__ flags) {
    if (flags[0]) return;
    int idx = blockIdx.x * 256 + threadIdx.x;
    const int n1 = 384 * 512;
    const int n2 = 128 * 320;
    if (idx < n1) {
        int n = idx >> 9, k = idx & 511;
        float v = (n < H1D && k < FIN) ? linW[(size_t)k * H1D + n] : 0.0f;
        unsigned short h, l;
        split2(v, h, l);
        Bt1[(size_t)n * 1024 + k] = h;
        Bt1[(size_t)n * 1024 + 512 + k] = l;
    } else if (idx < n1 + n2) {
        idx -= n1;
        int n = idx / 320, k = idx - n * 320;
        float v = (n < H2D && k < H1D) ? W1[(size_t)k * H2D + n] : 0.0f;
        unsigned short h, l;
        split2(v, h, l);
        Bt2[(size_t)n * 640 + k] = h;
        Bt2[(size_t)n * 640 + 320 + k] = l;
    }
}

// ---------- split-bf16 MFMA GEMM (fp32-accurate): C = A(fp32) @ W via Ahi*Bhi + Ahi*Blo + Alo*Bhi ----------
// R5-proven: tile 128x128, BK=32, 4 waves 2x2, single-buffer 32KB LDS (5 blocks/CU),
// T14 reg-prefetch, bijective XCD swizzle. (64KB dbuf regressed R4; no-LDS regressed R6.)
template <bool RELU, bool SCALE, bool HAS_BIAS, bool OUTBF>
__global__ __launch_bounds__(256) void k_gemm_mfma_split(const float* __restrict__ A,
                                                         const unsigned short* __restrict__ Bt,
                                                         const float* __restrict__ bias,
                                                         const float* __restrict__ dinv,
                                                         void* __restrict__ C,
                                                         int M, int K, int Kp, int Nn,
                                                         const int* __restrict__ flags) {
    if (flags[0]) return;
    __shared__ unsigned short As_hi[4096], As_lo[4096];  // 128 rows x 32 k, swizzled
    __shared__ unsigned short Bs_hi[4096], Bs_lo[4096];
    const int tid = threadIdx.x;
    const int nbx = gridDim.x;
    const int Wt = nbx * gridDim.y;
    const int li = blockIdx.x + nbx * blockIdx.y;
    const int q8 = Wt >> 3, r8 = Wt & 7;
    const int xk = li & 7, xj = li >> 3;
    const int wid = (xk < r8 ? xk * (q8 + 1) : r8 * (q8 + 1) + (xk - r8) * q8) + xj;
    const int n0 = (wid % nbx) * 128;
    const int m0 = (wid / nbx) * 128;
    const int w = tid >> 6, l = tid & 63;
    const int wm = (w >> 1) * 64, wn = (w & 1) * 64;
    const int lr = l & 15, ls = l >> 4;
    f32x4 acc[4][4] = {};

    float4 stA0, stA1, stA2, stA3;
    uint4  stB0, stB1, stB2, stB3;

#define LOAD_TILE(kc_)                                                              \
    {                                                                               \
        int kc = (kc_);                                                             \
        {                                                                           \
            int c, r, q, gm, gk;                                                    \
            c = tid;           r = c >> 3; q = c & 7; gm = m0 + r; gk = kc + q * 4; \
            stA0 = (gm < M && gk < K) ? *(const float4*)(A + (size_t)gm * K + gk) : make_float4(0.f,0.f,0.f,0.f); \
            c = tid + 256;     r = c >> 3; q = c & 7; gm = m0 + r; gk = kc + q * 4; \
            stA1 = (gm < M && gk < K) ? *(const float4*)(A + (size_t)gm * K + gk) : make_float4(0.f,0.f,0.f,0.f); \
            c = tid + 512;     r = c >> 3; q = c & 7; gm = m0 + r; gk = kc + q * 4; \
            stA2 = (gm < M && gk < K) ? *(const float4*)(A + (size_t)gm * K + gk) : make_float4(0.f,0.f,0.f,0.f); \
            c = tid + 768;     r = c >> 3; q = c & 7; gm = m0 + r; gk = kc + q * 4; \
            stA3 = (gm < M && gk < K) ? *(const float4*)(A + (size_t)gm * K + gk) : make_float4(0.f,0.f,0.f,0.f); \
        }                                                                           \
        {                                                                           \
            int c, r, q, gn;                                                        \
            c = tid;       r = c >> 2; q = c & 3; gn = n0 + r;                      \
            stB0 = *(const uint4*)(Bt + (size_t)gn * (2 * Kp) + kc + q * 8);        \
            c = tid + 256; r = c >> 2; q = c & 3; gn = n0 + r;                      \
            stB1 = *(const uint4*)(Bt + (size_t)gn * (2 * Kp) + kc + q * 8);        \
            c = tid;       r = c >> 2; q = c & 3; gn = n0 + r;                      \
            stB2 = *(const uint4*)(Bt + (size_t)gn * (2 * Kp) + Kp + kc + q * 8);   \
            c = tid + 256; r = c >> 2; q = c & 3; gn = n0 + r;                      \
            stB3 = *(const uint4*)(Bt + (size_t)gn * (2 * Kp) + Kp + kc + q * 8);   \
        }                                                                           \
    }

#define WRITE_TILE()                                                                \
    {                                                                               \
        float4 va[4] = {stA0, stA1, stA2, stA3};                                    \
        _Pragma("unroll")                                                           \
        for (int j = 0; j < 4; j++) {                                               \
            int c = tid + j * 256;                                                  \
            int r = c >> 3, q = c & 7;                                              \
            unsigned short h0,h1,h2,h3,l0,l1,l2,l3;                                 \
            split2(va[j].x, h0, l0); split2(va[j].y, h1, l1);                       \
            split2(va[j].z, h2, l2); split2(va[j].w, h3, l3);                       \
            int waddr = r * 64 + (((q >> 1) ^ ((r >> 1) & 3)) << 4) + ((q & 1) << 3); \
            *(ushort4*)((char*)As_hi + waddr) = make_ushort4(h0, h1, h2, h3);       \
            *(ushort4*)((char*)As_lo + waddr) = make_ushort4(l0, l1, l2, l3);       \
        }                                                                           \
        {                                                                           \
            int c, r, q, waddr;                                                     \
            c = tid;       r = c >> 2; q = c & 3; waddr = r * 64 + ((q ^ ((r >> 1) & 3)) << 4); \
            *(uint4*)((char*)Bs_hi + waddr) = stB0;                                 \
            c = tid + 256; r = c >> 2; q = c & 3; waddr = r * 64 + ((q ^ ((r >> 1) & 3)) << 4); \
            *(uint4*)((char*)Bs_hi + waddr) = stB1;                                 \
            c = tid;       r = c >> 2; q = c & 3; waddr = r * 64 + ((q ^ ((r >> 1) & 3)) << 4); \
            *(uint4*)((char*)Bs_lo + waddr) = stB2;                                 \
            c = tid + 256; r = c >> 2; q = c & 3; waddr = r * 64 + ((q ^ ((r >> 1) & 3)) << 4); \
            *(uint4*)((char*)Bs_lo + waddr) = stB3;                                 \
        }                                                                           \
    }

    const int nsteps = (K + 31) / 32;
    LOAD_TILE(0);
    for (int kt = 0; kt < nsteps; kt++) {
        WRITE_TILE();
        __syncthreads();
        if (kt + 1 < nsteps) LOAD_TILE((kt + 1) * 32);
        bf16x8 ah[4], al[4], bh[4], bl[4];
#pragma unroll
        for (int fm = 0; fm < 4; fm++) {
            int rr = wm + fm * 16 + lr;
            int addr = rr * 64 + ((ls ^ ((rr >> 1) & 3)) << 4);
            ah[fm] = *(const bf16x8*)((const char*)As_hi + addr);
            al[fm] = *(const bf16x8*)((const char*)As_lo + addr);
        }
#pragma unroll
        for (int fn = 0; fn < 4; fn++) {
            int cc2 = wn + fn * 16 + lr;
            int addr = cc2 * 64 + ((ls ^ ((cc2 >> 1) & 3)) << 4);
            bh[fn] = *(const bf16x8*)((const char*)Bs_hi + addr);
            bl[fn] = *(const bf16x8*)((const char*)Bs_lo + addr);
        }
#pragma unroll
        for (int fm = 0; fm < 4; fm++)
#pragma unroll
            for (int fn = 0; fn < 4; fn++) {
                acc[fm][fn] = __builtin_amdgcn_mfma_f32_16x16x32_bf16(ah[fm], bh[fn], acc[fm][fn], 0, 0, 0);
                acc[fm][fn] = __builtin_amdgcn_mfma_f32_16x16x32_bf16(ah[fm], bl[fn], acc[fm][fn], 0, 0, 0);
                acc[fm][fn] = __builtin_amdgcn_mfma_f32_16x16x32_bf16(al[fm], bh[fn], acc[fm][fn], 0, 0, 0);
            }
        __syncthreads();
    }
#undef LOAD_TILE
#undef WRITE_TILE

    // epilogue: C/D layout col=lane&15, row=(lane>>4)*4+reg [m89-verified]
#pragma unroll
    for (int fm = 0; fm < 4; fm++) {
#pragma unroll
        for (int j = 0; j < 4; j++) {
            int m = m0 + wm + fm * 16 + ls * 4 + j;
            if (m >= M) continue;
            float sc = SCALE ? dinv[m] : 1.0f;
#pragma unroll
            for (int fn = 0; fn < 4; fn++) {
                int n = n0 + wn + fn * 16 + lr;
                if (n >= Nn) continue;
                float v = acc[fm][fn][j];
                if (HAS_BIAS) v += bias[n];
                if (SCALE) v *= sc;
                if (RELU) v = fmaxf(v, 0.0f);
                if (OUTBF) ((__hip_bfloat16*)C)[(size_t)m * Nn + n] = __float2bfloat16(v);
                else       ((float*)C)[(size_t)m * Nn + n] = v;
            }
        }
    }
}

// ---------- agg1 + gemm3 fused: h2p = ((AGG(h1p)+b1).relu @ W2) * dinv ----------
// wave per node; gather 50 lanes (2 bf16 feats/lane); dot all 64 lanes via
// wave-local LDS row + shfl reduce. H2 never hits HBM. hi = lo + deg[node].
__global__ __launch_bounds__(256) void k_agg1_fused(const unsigned short* __restrict__ h1p_bf,
                                                    const int* __restrict__ row_ptr,
                                                    const int* __restrict__ deg,
                                                    const int* __restrict__ csr_src,
                                                    const float* __restrict__ dinv,
                                                    const void* __restrict__ b1,
                                                    const void* __restrict__ W2,
                                                    float* __restrict__ h2p,
                                                    const int* __restrict__ flags) {
    __shared__ float W2s[16][105];
    __shared__ float b1s[H2D];
    __shared__ float Hrow[4][H2D];
    const int bf = flags[0];
    const int tid = threadIdx.x;
    for (int i = tid; i < H2D * CC; i += 256) {
        int k = i >> 4, n = i & 15;
        W2s[n][k] = ldf(W2, i, bf);
    }
    for (int i = tid; i < H2D; i += 256) b1s[i] = ldf(b1, i, bf);
    __syncthreads();

    const int w = tid >> 6, lane = tid & 63;
    const int q = lane >> 4, n16 = lane & 15;
    const unsigned int* rows = (const unsigned int*)h1p_bf;  // 50 uints/node
    for (int node = blockIdx.x * 4 + w; node < NN; node += gridDim.x * 4) {
        float di = dinv[node];
        if (lane < 50) {
            float2 s = bf2f2(rows[(size_t)node * 50 + lane]);  // self loop
            float a0x = s.x, a0y = s.y;
            float a1x = 0.f, a1y = 0.f, a2x = 0.f, a2y = 0.f, a3x = 0.f, a3y = 0.f;
            int lo = row_ptr[node], hi = lo + deg[node];
            int e = lo;
            for (; e + 3 < hi; e += 4) {
                int s0 = csr_src[e], s1 = csr_src[e + 1], s2 = csr_src[e + 2], s3 = csr_src[e + 3];
                float2 v0 = bf2f2(rows[(size_t)s0 * 50 + lane]);
                float2 v1 = bf2f2(rows[(size_t)s1 * 50 + lane]);
                float2 v2 = bf2f2(rows[(size_t)s2 * 50 + lane]);
                float2 v3 = bf2f2(rows[(size_t)s3 * 50 + lane]);
                a0x += v0.x; a0y += v0.y;
                a1x += v1.x; a1y += v1.y;
                a2x += v2.x; a2y += v2.y;
                a3x += v3.x; a3y += v3.y;
            }
            for (; e < hi; e++) {
                float2 v = bf2f2(rows[(size_t)csr_src[e] * 50 + lane]);
                a0x += v.x; a0y += v.y;
            }
            float sx = (a0x + a1x) + (a2x + a3x);
            float sy = (a0y + a1y) + (a2y + a3y);
            int f = lane * 2;
            Hrow[w][f]     = fmaxf(sx * di + b1s[f], 0.0f);
            Hrow[w][f + 1] = fmaxf(sy * di + b1s[f + 1], 0.0f);
        }
        __builtin_amdgcn_sched_barrier(0);  // wave-local LDS ops stay ordered
        float acc2 = 0.0f;
#pragma unroll
        for (int j = 0; j < 25; j++) {
            int k = q * 25 + j;
            acc2 += Hrow[w][k] * W2s[n16][k];
        }
        acc2 += __shfl_xor(acc2, 16);
        acc2 += __shfl_xor(acc2, 32);
        if (lane < 16) h2p[(size_t)node * CC + n16] = acc2 * di;
        __builtin_amdgcn_sched_barrier(0);
    }
}

// ---------- aggregation 2 + bias + log_softmax ----------
__global__ __launch_bounds__(256) void k_agg2(const float* __restrict__ h2p,
                                              const int* __restrict__ row_ptr,
                                              const int* __restrict__ deg,
                                              const int* __restrict__ csr_src,
                                              const float* __restrict__ dinv,
                                              const void* __restrict__ b2,
                                              void* __restrict__ out,
                                              const int* __restrict__ flags) {
    int tid = threadIdx.x;
    int n = tid & 15;
    int g = tid >> 4;
    int node = blockIdx.x * 16 + g;
    if (node >= NN) return;
    const int bf = flags[0];
    float a0 = h2p[(size_t)node * CC + n];
    float a1 = 0.f, a2 = 0.f, a3 = 0.f;
    int lo = row_ptr[node], hi = lo + deg[node];
    int e = lo;
    for (; e + 3 < hi; e += 4) {
        int s0 = csr_src[e], s1 = csr_src[e + 1], s2 = csr_src[e + 2], s3 = csr_src[e + 3];
        a0 += h2p[(size_t)s0 * CC + n];
        a1 += h2p[(size_t)s1 * CC + n];
        a2 += h2p[(size_t)s2 * CC + n];
        a3 += h2p[(size_t)s3 * CC + n];
    }
    for (; e < hi; e++) a0 += h2p[(size_t)csr_src[e] * CC + n];
    float acc = (a0 + a1) + (a2 + a3);
    float logit = acc * dinv[node] + ldf(b2, n, bf);
    float m = logit;
#pragma unroll
    for (int off = 1; off < 16; off <<= 1) m = fmaxf(m, __shfl_xor(m, off, 16));
    float ex = __expf(logit - m);
    float ssum = ex;
#pragma unroll
    for (int off = 1; off < 16; off <<= 1) ssum += __shfl_xor(ssum, off, 16);
    float r = logit - m - __logf(ssum);
    size_t oidx = (size_t)node * CC + n;
    if (bf) ((__hip_bfloat16*)out)[oidx] = __float2bfloat16(r);
    else    ((float*)out)[oidx] = r;
}

extern "C" void kernel_launch(void* const* d_in, const int* in_sizes, int n_in,
                              void* d_out, int out_size, void* d_ws, size_t ws_size,
                              hipStream_t stream) {
    const void* x     = d_in[0];
    const void* lin_W = d_in[1];
    const void* lin_b = d_in[2];
    const void* W1    = d_in[3];
    const void* b1    = d_in[4];
    const void* W2    = d_in[5];
    const void* b2    = d_in[6];
    const int*  ei    = (const int*)d_in[7];

    char* ws = (char*)d_ws;
    size_t off = 0;
    auto alloc = [&](size_t bytes) {
        off = (off + 255) & ~(size_t)255;
        void* p = ws + off;
        off += bytes;
        return p;
    };
    int*   flags   = (int*)alloc(2 * 4);
    int*   total   = (int*)alloc(4);
    int*   cnt     = (int*)alloc((size_t)NN * 4);   // becomes deg after scatter
    int*   row_ptr = (int*)alloc((size_t)NN * 4);
    int*   csr_src = (int*)alloc((size_t)EE * 4);
    float* dinv    = (float*)alloc((size_t)NN * 4);
    float* H1      = (float*)alloc((size_t)NN * H1D * 4);              // 60 MB fp32
    unsigned short* H1p = (unsigned short*)alloc((size_t)NN * H2D * 2);  // 10 MB bf16
    float* h2p     = (float*)alloc((size_t)NN * CC * 4);               // 3.2 MB
    unsigned short* Bt1 = (unsigned short*)alloc((size_t)384 * 1024 * 2);
    unsigned short* Bt2 = (unsigned short*)alloc((size_t)128 * 640 * 2);

    const int gN = (NN + 255) / 256;
    const int gE = (EE + 255) / 256;

    // init (sniff + zero cnt + zero total)
    k_init<<<gN + 1, 256, 0, stream>>>((const unsigned short*)x, (const unsigned int*)ei,
                                       flags, cnt, total);
    // CSR + degrees
    k_hist<<<gE, 256, 0, stream>>>(ei, cnt, flags);
    k_scan_mb<<<gN, 256, 0, stream>>>(cnt, row_ptr, dinv, total);
    k_scatter<<<gE, 256, 0, stream>>>(ei, row_ptr, cnt, csr_src, flags);

    // fused weight prep (no-op in bf16 mode)
    k_prep_both<<<(384 * 512 + 128 * 320 + 255) / 256, 256, 0, stream>>>(
        (const float*)lin_W, (const float*)W1, Bt1, Bt2, flags);

    // H1 = relu(x @ lin_W + lin_b)
    k_gemm_mfma_split<true, false, true, false><<<dim3(3, (NN + 127) / 128), 256, 0, stream>>>(
        (const float*)x, Bt1, (const float*)lin_b, nullptr, H1, NN, FIN, 512, H1D, flags);
    {   // bf16-input fallback (early-exits in fp32 mode)
        dim3 grid((NN + 63) / 64, (H1D + 63) / 64);
        k_gemm<true, true, false, false><<<grid, 256, 0, stream>>>(
            x, lin_W, lin_b, nullptr, H1, NN, FIN, H1D, flags);
    }

    // H1p = (H1 @ W1) * dinv[row] -> bf16 packed
    k_gemm_mfma_split<false, true, false, true><<<dim3(1, (NN + 127) / 128), 256, 0, stream>>>(
        H1, Bt2, nullptr, dinv, H1p, NN, H1D, 320, H2D, flags);
    {   // bf16-input fallback
        dim3 grid((NN + 63) / 64, (H2D + 63) / 64);
        k_gemm<false, false, true, true><<<grid, 256, 0, stream>>>(
            H1, W1, nullptr, dinv, H1p, NN, H1D, H2D, flags);
    }

    // h2p = relu(dinv*AGG(H1p)+b1) @ W2 * dinv  (gemm3 fused; H2 never materialized)
    k_agg1_fused<<<2048, 256, 0, stream>>>(H1p, row_ptr, cnt, csr_src, dinv, b1, W2, h2p, flags);
    // out = log_softmax(dinv * (gather-sum h2p) + b2)
    k_agg2<<<(NN + 15) / 16, 256, 0, stream>>>(h2p, row_ptr, cnt, csr_src, dinv, b2, d_out, flags);
}